// Round 2
// baseline (428.631 us; speedup 1.0000x reference)
//
#include <hip/hip_runtime.h>

#define HDIM 1024
#define VD   32000
#define WINN 129
#define NEGV (-1e30f)

// ws float offsets
#define X_     0        // 1024: h_l0, later fc1 output
#define HT_    1024     // 1024: h_t (layer-1 h)
#define G_     5120     // 4096: layer-1 pre-gates (whh1@h0[1] + biases)
#define ATT1_  9216     // 512
#define CAT_   9728     // 2048: [ctx | h_t]
#define PARTM_ 12000    // 1000 per-block maxes
#define PARTS_ 13000    // 1000 per-block sumexps
#define LOG_   16384    // 32000 logits

// d_out float element offsets
#define O_Y   0
#define O_OUT 32000
#define O_HN  33024
#define O_CN  35072
#define O_A   37120

__device__ __forceinline__ float wred(float v){
  #pragma unroll
  for(int off=32; off; off>>=1) v += __shfl_xor(v, off, 64);
  return v;
}
__device__ __forceinline__ float wmax(float v){
  #pragma unroll
  for(int off=32; off; off>>=1) v = fmaxf(v, __shfl_xor(v, off, 64));
  return v;
}
__device__ __forceinline__ float sigf(float x){ return 1.f/(1.f+expf(-x)); }
__device__ __forceinline__ float dot4(float4 a, float4 b){
  return a.x*b.x + a.y*b.y + a.z*b.z + a.w*b.w;
}
__device__ __forceinline__ float4 ld4(const float* p){ return *(const float4*)p; }

// ---- kernels ----

// Stream a weight array through L2/L3 so the later consumer hits Infinity
// Cache instead of HBM. Runs on a parallel graph branch, concurrent with the
// serial LSTM/attention chain (fills BW-idle bubbles). Read-and-discard;
// asm keeps the loads live (rule: ablation-via-skip DCEs upstream ops).
__global__ __launch_bounds__(256) void k_prefetch(const float* __restrict__ a, long n4){
  long i = (long)blockIdx.x*256 + threadIdx.x;
  long stride = (long)gridDim.x*256;
  float acc = 0.f;
  for (; i < n4; i += stride){
    float4 v = ld4(a + (i<<2));
    acc += v.x + v.y + v.z + v.w;
  }
  asm volatile("" :: "v"(acc));
}

// Layer-0 LSTM, fully fused: one wave owns hidden unit j.
// Computes all 4 gates (wih0 rows, whh0 rows), applies activation in-wave,
// AND precomputes layer-1's whh1@h0[1] gate partials (independent of layer-0 out).
__global__ __launch_bounds__(256) void k_lstm0(
    const float* __restrict__ wih, const float* __restrict__ whh,
    const float* __restrict__ bih, const float* __restrict__ bhh,
    const int* __restrict__ word, const float* __restrict__ emb,
    const float* __restrict__ h0, const float* __restrict__ c0,
    float* __restrict__ ws, float* __restrict__ hn, float* __restrict__ cn){
  int j = blockIdx.x*4 + (threadIdx.x>>6);   // 0..1023
  int lane = threadIdx.x & 63;
  const float* x    = emb + ((size_t)word[0]<<10);
  const float* h00  = h0;
  const float* h01  = h0 + HDIM;
  const float* wih0 = wih + ((size_t)j<<10);
  const float* whh0 = whh + ((size_t)j<<10);
  const float* whh1 = whh + ((size_t)(4096 + j)<<10);
  float acc[12];
  #pragma unroll
  for (int g=0; g<12; g++) acc[g]=0.f;
  #pragma unroll
  for (int c=0;c<4;c++){
    int o = lane*4 + 256*c;
    float4 xv = ld4(x+o), av = ld4(h00+o), bv = ld4(h01+o);
    #pragma unroll
    for (int g=0; g<4; g++){
      acc[g]   += dot4(ld4(wih0 + ((size_t)g<<20) + o), xv);
      acc[4+g] += dot4(ld4(whh0 + ((size_t)g<<20) + o), av);
      acc[8+g] += dot4(ld4(whh1 + ((size_t)g<<20) + o), bv);
    }
  }
  #pragma unroll
  for (int g=0; g<12; g++) acc[g] = wred(acc[g]);
  if (lane==0){
    float gi = acc[0]+acc[4] + bih[j]      + bhh[j];
    float gf = acc[1]+acc[5] + bih[1024+j] + bhh[1024+j];
    float gg = acc[2]+acc[6] + bih[2048+j] + bhh[2048+j];
    float go = acc[3]+acc[7] + bih[3072+j] + bhh[3072+j];
    float cc = sigf(gf)*c0[j] + sigf(gi)*tanhf(gg);
    float hh = sigf(go)*tanhf(cc);
    ws[X_+j] = hh; hn[j]=hh; cn[j]=cc;
    #pragma unroll
    for (int g=0; g<4; g++)
      ws[G_ + g*1024 + j] = acc[8+g] + bih[4096 + g*1024 + j] + bhh[4096 + g*1024 + j];
  }
}

// Layer-1 LSTM: only the wih1@h_l0 half remains (16.7 MB), act fused.
__global__ __launch_bounds__(256) void k_lstm1(
    const float* __restrict__ wih1, const float* __restrict__ c0l,
    float* __restrict__ ws, float* __restrict__ hn, float* __restrict__ cn){
  int j = blockIdx.x*4 + (threadIdx.x>>6);
  int lane = threadIdx.x & 63;
  const float* wr = wih1 + ((size_t)j<<10);
  float acc[4] = {0.f,0.f,0.f,0.f};
  #pragma unroll
  for (int c=0;c<4;c++){
    int o = lane*4 + 256*c;
    float4 hv = ld4(ws + X_ + o);
    #pragma unroll
    for (int g=0; g<4; g++)
      acc[g] += dot4(ld4(wr + ((size_t)g<<20) + o), hv);
  }
  #pragma unroll
  for (int g=0; g<4; g++) acc[g]=wred(acc[g]);
  if (lane==0){
    float gi = acc[0] + ws[G_ + j];
    float gf = acc[1] + ws[G_ + 1024 + j];
    float gg = acc[2] + ws[G_ + 2048 + j];
    float go = acc[3] + ws[G_ + 3072 + j];
    float cc = sigf(gf)*c0l[j] + sigf(gi)*tanhf(gg);
    float hh = sigf(go)*tanhf(cc);
    ws[HT_+j]=hh; ws[CAT_+HDIM+j]=hh; hn[j]=hh; cn[j]=cc;
  }
}

__global__ __launch_bounds__(256) void k_att1(const float* __restrict__ w,
    const float* __restrict__ b, float* __restrict__ ws){
  int gid = blockIdx.x*256 + threadIdx.x;
  int r = gid >> 6, lane = gid & 63;      // r in 0..511
  const float* wr = w + ((size_t)r<<10);
  float acc = 0.f;
  #pragma unroll
  for (int j=0; j<4; j++){
    int o = lane*4 + 256*j;
    acc += dot4(ld4(wr+o), ld4(ws+HT_+o));
  }
  acc = wred(acc);
  if (lane==0) ws[ATT1_ + r] = tanhf(acc + b[r]);
}

// p + 129 score rows + softmax + gauss + ctx, all in one block.
__global__ __launch_bounds__(1024) void k_attn(const float* __restrict__ enc,
    const int* __restrict__ slen, const float* __restrict__ a2w,
    const float* __restrict__ a2b, float* __restrict__ ws, float* __restrict__ aout){
  __shared__ float sarr[WINN];
  __shared__ float av[WINN];
  __shared__ int   ci[WINN];
  __shared__ float red[2];
  __shared__ float pinfo[1];
  __shared__ int   iw[2];
  int t = threadIdx.x, lane = t & 63, wv = t >> 6;
  float Sf = (float)slen[0];
  int smax = slen[0]-1;
  if (wv==0){
    float pacc = 0.f;
    #pragma unroll
    for (int c=0;c<2;c++){
      int o = lane*4 + 256*c;
      pacc += dot4(ld4(a2w+o), ld4(ws+ATT1_+o));
    }
    pacc = wred(pacc);
    float p = Sf * sigf(pacc + a2b[0]);
    if (t==0){
      pinfo[0] = p;
      iw[0] = (int)rintf(fmaxf(p-64.f,0.f));
      iw[1] = (int)rintf(fminf(p+64.f, Sf-1.f));
    }
  }
  __syncthreads();
  float p = pinfo[0];
  int wsi = iw[0], wei = iw[1];
  // scores: wave wv handles rows wv, wv+16, ...
  for (int k = wv; k < WINN; k += 16){
    int idx = wsi + k;
    int c = idx > smax ? smax : idx;
    const float* er = enc + ((size_t)c<<10);
    float acc=0.f;
    #pragma unroll
    for (int cc=0;cc<4;cc++){
      int o = lane*4 + 256*cc;
      acc += dot4(ld4(er+o), ld4(ws+HT_+o));
    }
    acc = wred(acc);
    if (lane==0){
      sarr[k] = (idx<=wei)? acc : NEGV;
      ci[k] = c;
    }
  }
  __syncthreads();
  if (t < 64){
    float m = fmaxf(sarr[t], sarr[t+64]);
    if (t==0) m = fmaxf(m, sarr[128]);
    m = wmax(m);
    if (t==0) red[0]=m;
  }
  __syncthreads();
  float M = red[0];
  if (t < 64){
    float e = expf(sarr[t]-M) + expf(sarr[t+64]-M);
    if (t==0) e += expf(sarr[128]-M);
    e = wred(e);
    if (t==0) red[1]=e;
  }
  __syncthreads();
  float sm = red[1];
  if (t < WINN){
    int idx = wsi + t;
    float a = expf(sarr[t]-M)/sm;
    a = (idx<=wei) ? a*expf(((float)idx - p)*(1.f/2048.f)) : 0.f;
    av[t]=a; aout[t]=a;
  }
  __syncthreads();
  // ctx: thread t computes element t (enc window is L1/L2-hot from score pass)
  float acc=0.f;
  for (int k=0;k<WINN;k++) acc += av[k]*enc[((size_t)ci[k]<<10)+t];
  ws[CAT_+t]=acc;
}

__global__ __launch_bounds__(256) void k_fc1(const float* __restrict__ w,
    const float* __restrict__ b, float* __restrict__ ws, float* __restrict__ oout){
  int gid = blockIdx.x*256 + threadIdx.x;
  int r = gid >> 6, lane = gid & 63;      // r in 0..1023
  const float* wr = w + ((size_t)r<<11);
  float acc = 0.f;
  #pragma unroll
  for (int j=0; j<8; j++){
    int o = lane*4 + 256*j;
    acc += dot4(ld4(wr+o), ld4(ws+CAT_+o));
  }
  acc = wred(acc);
  if (lane==0){
    float o = tanhf(acc + b[r]);
    ws[X_ + r] = o;
    oout[r] = o;
  }
}

// fc2 + fused per-block LSE partial: block b owns rows [32b, 32b+32),
// each wave carries 4 consecutive rows (deep load pipeline).
__global__ __launch_bounds__(512) void k_fc2(const float* __restrict__ w,
    const float* __restrict__ b, float* __restrict__ ws){
  __shared__ float lg[32];
  int wv = threadIdx.x >> 6, lane = threadIdx.x & 63;
  int r0 = (blockIdx.x*8 + wv)*4;
  const float* wr = w + ((size_t)r0<<10);
  float acc[4]={0.f,0.f,0.f,0.f};
  #pragma unroll
  for (int c=0;c<4;c++){
    int o = lane*4 + 256*c;
    float4 xv = ld4(ws+X_+o);
    #pragma unroll
    for (int rr=0;rr<4;rr++)
      acc[rr] += dot4(ld4(wr + ((size_t)rr<<10) + o), xv);
  }
  #pragma unroll
  for (int rr=0;rr<4;rr++) acc[rr]=wred(acc[rr]);
  if (lane==0){
    #pragma unroll
    for (int rr=0;rr<4;rr++){
      float v = acc[rr] + b[r0+rr];
      ws[LOG_+r0+rr] = v;
      lg[wv*4+rr] = v;
    }
  }
  __syncthreads();
  int t = threadIdx.x;
  if (t < 64){
    float v = (t<32)? lg[t] : -INFINITY;
    float m = wmax(v);
    float e = (t<32)? expf(lg[t]-m) : 0.f;
    float s = wred(e);
    if (t==0){
      ws[PARTM_ + blockIdx.x] = m;
      ws[PARTS_ + blockIdx.x] = s;
    }
  }
}

// Reduce 1000 partials (L2-hot) + write normalized y.
__global__ __launch_bounds__(256) void k_y(const float* __restrict__ ws, float* __restrict__ y){
  __shared__ float rm[4], rs[4];
  int t = threadIdx.x, lane = t&63, wv = t>>6;
  float m = -INFINITY;
  for (int k=t;k<1000;k+=256) m = fmaxf(m, ws[PARTM_+k]);
  m = wmax(m);
  if (lane==0) rm[wv]=m;
  __syncthreads();
  float M = fmaxf(fmaxf(rm[0],rm[1]), fmaxf(rm[2],rm[3]));
  float s = 0.f;
  for (int k=t;k<1000;k+=256) s += ws[PARTS_+k]*expf(ws[PARTM_+k]-M);
  s = wred(s);
  if (lane==0) rs[wv]=s;
  __syncthreads();
  float S = rs[0]+rs[1]+rs[2]+rs[3];
  float off = M + logf(S);
  int i = blockIdx.x*256 + t;   // float4 index, need 8000
  if (i < 8000){
    float4 v = ld4(ws + LOG_ + i*4);
    v.x-=off; v.y-=off; v.z-=off; v.w-=off;
    *(float4*)(y + i*4) = v;
  }
}

// Persistent side-stream + events for the parallel prefetch branch.
// Created once (host objects; legal to create during graph capture — they
// are not captured stream-ops). Fork/join via events is the documented
// multi-stream graph-capture pattern.
static hipStream_t g_s2  = nullptr;
static hipEvent_t  g_evf = nullptr;
static hipEvent_t  g_evj = nullptr;

extern "C" void kernel_launch(void* const* d_in, const int* in_sizes, int n_in,
                              void* d_out, int out_size, void* d_ws, size_t ws_size,
                              hipStream_t stream) {
  const int*   slen = (const int*)d_in[0];
  const float* enc  = (const float*)d_in[1];
  const int*   word = (const int*)d_in[2];
  const float* h0   = (const float*)d_in[3];
  const float* c0   = (const float*)d_in[4];
  const float* emb  = (const float*)d_in[5];
  const float* wih  = (const float*)d_in[6];
  const float* whh  = (const float*)d_in[7];
  const float* bih  = (const float*)d_in[8];
  const float* bhh  = (const float*)d_in[9];
  const float* a1w  = (const float*)d_in[10];
  const float* a1b  = (const float*)d_in[11];
  const float* a2w  = (const float*)d_in[12];
  const float* a2b  = (const float*)d_in[13];
  const float* f1w  = (const float*)d_in[14];
  const float* f1b  = (const float*)d_in[15];
  const float* f2w  = (const float*)d_in[16];
  const float* f2b  = (const float*)d_in[17];
  float* ws  = (float*)d_ws;
  float* out = (float*)d_out;

  if (!g_s2){
    hipStreamCreateWithFlags(&g_s2, hipStreamNonBlocking);
    hipEventCreateWithFlags(&g_evf, hipEventDisableTiming);
    hipEventCreateWithFlags(&g_evj, hipEventDisableTiming);
  }

  // Fork: prefetch fc1/fc2 weights (139 MB) into L2/L3 concurrently with the
  // serial chain. Fills HBM-idle bubbles; k_fc1/k_fc2 then read cache-hot.
  hipEventRecord(g_evf, stream);
  hipStreamWaitEvent(g_s2, g_evf, 0);
  k_prefetch<<<256,256,0,g_s2>>>(f1w, (long)(HDIM*2*HDIM/4));
  k_prefetch<<<512,256,0,g_s2>>>(f2w, (long)VD*HDIM/4);
  hipEventRecord(g_evj, g_s2);

  k_lstm0<<<256,256,0,stream>>>(wih, whh, bih, bhh, word, emb, h0, c0,
                                ws, out + O_HN, out + O_CN);
  k_lstm1<<<256,256,0,stream>>>(wih + (size_t)4096*1024, c0 + HDIM,
                                ws, out + O_HN + HDIM, out + O_CN + HDIM);
  k_att1<<<128,256,0,stream>>>(a1w, a1b, ws);
  k_attn<<<1,1024,0,stream>>>(enc, slen, a2w, a2b, ws, out + O_A);
  k_fc1<<<256,256,0,stream>>>(f1w, f1b, ws, out + O_OUT);
  k_fc2<<<1000,512,0,stream>>>(f2w, f2b, ws);

  // Join the prefetch branch before the final (tiny) kernel.
  hipStreamWaitEvent(stream, g_evj, 0);
  k_y<<<32,256,0,stream>>>(ws, out + O_Y);
}

// Round 3
// 360.413 us; speedup vs baseline: 1.1893x; 1.1893x over previous
//
#include <hip/hip_runtime.h>

#define HDIM 1024
#define VD   32000
#define WINN 129
#define NEGV (-1e30f)

// ws float offsets
#define X_     0        // 1024: h_l0, later fc1 output
#define HT_    1024     // 1024: h_t (layer-1 h)
#define G_     5120     // 4096: layer-1 pre-gates (whh1@h0[1] + biases)
#define ATT1_  9216     // 512
#define CAT_   9728     // 2048: [ctx | h_t]
#define A_     11776    // 129: raw scores
#define SC_    11908    // p
#define IW_    11912    // int slots: ws_i, we_i
#define PARTM_ 12000    // 1000 per-block maxes
#define PARTS_ 13000    // 1000 per-block sumexps
#define LOG_   16384    // 32000 logits

// d_out float element offsets
#define O_Y   0
#define O_OUT 32000
#define O_HN  33024
#define O_CN  35072
#define O_A   37120

__device__ __forceinline__ float wred(float v){
  #pragma unroll
  for(int off=32; off; off>>=1) v += __shfl_xor(v, off, 64);
  return v;
}
__device__ __forceinline__ float wmax(float v){
  #pragma unroll
  for(int off=32; off; off>>=1) v = fmaxf(v, __shfl_xor(v, off, 64));
  return v;
}
__device__ __forceinline__ float sigf(float x){ return 1.f/(1.f+expf(-x)); }
__device__ __forceinline__ float dot4(float4 a, float4 b){
  return a.x*b.x + a.y*b.y + a.z*b.z + a.w*b.w;
}
__device__ __forceinline__ float4 ld4(const float* p){ return *(const float4*)p; }

// ---- kernels ----

// Layer-0 LSTM: one BLOCK per hidden unit j; the unit's 12 row-dots
// (wih0 i/f/g/o, whh0 i/f/g/o, whh1 i/f/g/o precompute) are K-split across
// the block's 4 waves (256 cols each) -> 4096 waves total (4/SIMD) for
// latency hiding, vs 1 wave/SIMD in the previous fused version.
__global__ __launch_bounds__(256) void k_lstm0(
    const float* __restrict__ wih, const float* __restrict__ whh,
    const float* __restrict__ bih, const float* __restrict__ bhh,
    const int* __restrict__ word, const float* __restrict__ emb,
    const float* __restrict__ h0, const float* __restrict__ c0,
    float* __restrict__ ws, float* __restrict__ hn, float* __restrict__ cn){
  __shared__ float part[4][12];
  int j = blockIdx.x;                      // hidden unit 0..1023
  int kq = threadIdx.x >> 6, lane = threadIdx.x & 63;
  const float* x    = emb + ((size_t)word[0]<<10);
  const float* h01  = h0 + HDIM;
  const float* wih0 = wih + ((size_t)j<<10);
  const float* whh0 = whh + ((size_t)j<<10);
  const float* whh1 = whh + ((size_t)(4096 + j)<<10);
  int o = kq*256 + lane*4;
  float4 xv = ld4(x+o), av = ld4(h0+o), bv = ld4(h01+o);
  float acc[12];
  #pragma unroll
  for (int g=0; g<4; g++){
    acc[g]   = dot4(ld4(wih0 + ((size_t)g<<20) + o), xv);
    acc[4+g] = dot4(ld4(whh0 + ((size_t)g<<20) + o), av);
    acc[8+g] = dot4(ld4(whh1 + ((size_t)g<<20) + o), bv);
  }
  #pragma unroll
  for (int g=0; g<12; g++) acc[g] = wred(acc[g]);
  if (lane==0){
    #pragma unroll
    for (int g=0; g<12; g++) part[kq][g] = acc[g];
  }
  __syncthreads();
  if (threadIdx.x==0){
    float s[12];
    #pragma unroll
    for (int g=0; g<12; g++) s[g] = part[0][g]+part[1][g]+part[2][g]+part[3][g];
    float gi = s[0]+s[4] + bih[j]      + bhh[j];
    float gf = s[1]+s[5] + bih[1024+j] + bhh[1024+j];
    float gg = s[2]+s[6] + bih[2048+j] + bhh[2048+j];
    float go = s[3]+s[7] + bih[3072+j] + bhh[3072+j];
    float cc = sigf(gf)*c0[j] + sigf(gi)*tanhf(gg);
    float hh = sigf(go)*tanhf(cc);
    ws[X_+j] = hh; hn[j]=hh; cn[j]=cc;
    #pragma unroll
    for (int g=0; g<4; g++)
      ws[G_ + g*1024 + j] = s[8+g] + bih[4096 + g*1024 + j] + bhh[4096 + g*1024 + j];
  }
}

// Layer-1 LSTM: same one-block-per-unit K-split structure; only the
// wih1@h_l0 half remains (whh1@h0[1] was precomputed into G_).
__global__ __launch_bounds__(256) void k_lstm1(
    const float* __restrict__ wih1, const float* __restrict__ c0l,
    float* __restrict__ ws, float* __restrict__ hn, float* __restrict__ cn){
  __shared__ float part[4][4];
  int j = blockIdx.x;                      // hidden unit 0..1023
  int kq = threadIdx.x >> 6, lane = threadIdx.x & 63;
  const float* wr = wih1 + ((size_t)j<<10);
  int o = kq*256 + lane*4;
  float4 hv = ld4(ws + X_ + o);
  float acc[4];
  #pragma unroll
  for (int g=0; g<4; g++)
    acc[g] = dot4(ld4(wr + ((size_t)g<<20) + o), hv);
  #pragma unroll
  for (int g=0; g<4; g++) acc[g] = wred(acc[g]);
  if (lane==0){
    #pragma unroll
    for (int g=0; g<4; g++) part[kq][g] = acc[g];
  }
  __syncthreads();
  if (threadIdx.x==0){
    float s[4];
    #pragma unroll
    for (int g=0; g<4; g++) s[g] = part[0][g]+part[1][g]+part[2][g]+part[3][g];
    float gi = s[0] + ws[G_ + j];
    float gf = s[1] + ws[G_ + 1024 + j];
    float gg = s[2] + ws[G_ + 2048 + j];
    float go = s[3] + ws[G_ + 3072 + j];
    float cc = sigf(gf)*c0l[j] + sigf(gi)*tanhf(gg);
    float hh = sigf(go)*tanhf(cc);
    ws[HT_+j]=hh; ws[CAT_+HDIM+j]=hh; hn[j]=hh; cn[j]=cc;
  }
}

__global__ __launch_bounds__(256) void k_att1(const float* __restrict__ w,
    const float* __restrict__ b, float* __restrict__ ws){
  int gid = blockIdx.x*256 + threadIdx.x;
  int r = gid >> 6, lane = gid & 63;      // r in 0..511
  const float* wr = w + ((size_t)r<<10);
  float acc = 0.f;
  #pragma unroll
  for (int j=0; j<4; j++){
    int o = lane*4 + 256*j;
    acc += dot4(ld4(wr+o), ld4(ws+HT_+o));
  }
  acc = wred(acc);
  if (lane==0) ws[ATT1_ + r] = tanhf(acc + b[r]);
}

// p (redundant per wave) + 129 score rows, spread across 33 blocks so the
// 516 KB enc window is pulled by ~33 CUs in parallel, not 1.
__global__ __launch_bounds__(256) void k_scores(const float* __restrict__ enc,
    const int* __restrict__ slen, const float* __restrict__ a2w,
    const float* __restrict__ a2b, float* __restrict__ ws){
  int t = threadIdx.x;
  int lane = t & 63;
  float pacc = 0.f;
  #pragma unroll
  for (int c=0; c<2; c++){
    int o = lane*4 + 256*c;
    pacc += dot4(ld4(a2w+o), ld4(ws+ATT1_+o));
  }
  pacc = wred(pacc);
  float Sf = (float)slen[0];
  float p  = Sf * sigf(pacc + a2b[0]);
  int wsi = (int)rintf(fmaxf(p - 64.f, 0.f));
  int wei = (int)rintf(fminf(p + 64.f, Sf - 1.f));
  if (blockIdx.x==0 && t==0){
    ws[SC_] = p;
    ((int*)ws)[IW_]   = wsi;
    ((int*)ws)[IW_+1] = wei;
  }
  int k = blockIdx.x*4 + (t>>6);
  if (k >= WINN) return;
  int idx = wsi + k;
  int smax = slen[0]-1;
  int ci = idx > smax ? smax : idx;
  const float* er = enc + ((size_t)ci<<10);
  float acc = 0.f;
  #pragma unroll
  for (int c=0; c<4; c++){
    int o = lane*4 + 256*c;
    acc += dot4(ld4(er+o), ld4(ws+HT_+o));
  }
  acc = wred(acc);
  if (lane==0) ws[A_ + k] = (idx <= wei) ? acc : NEGV;
}

// Softmax (redundant, trivial) + 128 ctx elements per block; 8 blocks so
// the ctx column pass is spread across 8 CUs instead of 1.
__global__ __launch_bounds__(128) void k_smctx(const float* __restrict__ enc,
    const int* __restrict__ slen, float* __restrict__ ws, float* __restrict__ aout){
  __shared__ float av[WINN];
  __shared__ float red[2];
  int t = threadIdx.x;
  float p = ws[SC_];
  int wsi = ((int*)ws)[IW_], wei = ((int*)ws)[IW_+1];
  int smax = slen[0]-1;
  if (t < 64){
    float s0 = ws[A_+t], s1 = ws[A_+64+t];
    float m = fmaxf(s0, s1);
    if (t==0) m = fmaxf(m, ws[A_+128]);
    m = wmax(m);
    if (t==0) red[0] = m;
  }
  __syncthreads();
  float M = red[0];
  if (t < 64){
    float s0 = ws[A_+t], s1 = ws[A_+64+t];
    float e = expf(s0-M) + expf(s1-M);
    if (t==0) e += expf(ws[A_+128]-M);
    e = wred(e);
    if (t==0) red[1] = e;
  }
  __syncthreads();
  float sm = red[1];
  if (t < 64){
    for (int k=t; k<WINN; k+=64){
      int idx = wsi + k;
      float a = expf(ws[A_+k]-M)/sm;
      a = (idx <= wei) ? a*expf(((float)idx - p)*(1.f/2048.f)) : 0.f;
      av[k] = a;
      if (blockIdx.x==0) aout[k] = a;
    }
  }
  __syncthreads();
  int tout = blockIdx.x*128 + t;
  float acc = 0.f;
  for (int k=0; k<WINN; k++){
    int idx = wsi + k;
    int c = idx > smax ? smax : idx;
    acc += av[k]*enc[((size_t)c<<10) + tout];
  }
  ws[CAT_+tout] = acc;
}

__global__ __launch_bounds__(256) void k_fc1(const float* __restrict__ w,
    const float* __restrict__ b, float* __restrict__ ws, float* __restrict__ oout){
  int gid = blockIdx.x*256 + threadIdx.x;
  int r = gid >> 6, lane = gid & 63;      // r in 0..1023
  const float* wr = w + ((size_t)r<<11);
  float acc = 0.f;
  #pragma unroll
  for (int j=0; j<8; j++){
    int o = lane*4 + 256*j;
    acc += dot4(ld4(wr+o), ld4(ws+CAT_+o));
  }
  acc = wred(acc);
  if (lane==0){
    float o = tanhf(acc + b[r]);
    ws[X_ + r] = o;
    oout[r] = o;
  }
}

// fc2 + fused per-block LSE partial: block b owns rows [32b, 32b+32),
// each wave carries 4 consecutive rows (deep load pipeline).
__global__ __launch_bounds__(512) void k_fc2(const float* __restrict__ w,
    const float* __restrict__ b, float* __restrict__ ws){
  __shared__ float lg[32];
  int wv = threadIdx.x >> 6, lane = threadIdx.x & 63;
  int r0 = (blockIdx.x*8 + wv)*4;
  const float* wr = w + ((size_t)r0<<10);
  float acc[4]={0.f,0.f,0.f,0.f};
  #pragma unroll
  for (int c=0;c<4;c++){
    int o = lane*4 + 256*c;
    float4 xv = ld4(ws+X_+o);
    #pragma unroll
    for (int rr=0;rr<4;rr++)
      acc[rr] += dot4(ld4(wr + ((size_t)rr<<10) + o), xv);
  }
  #pragma unroll
  for (int rr=0;rr<4;rr++) acc[rr]=wred(acc[rr]);
  if (lane==0){
    #pragma unroll
    for (int rr=0;rr<4;rr++){
      float v = acc[rr] + b[r0+rr];
      ws[LOG_+r0+rr] = v;
      lg[wv*4+rr] = v;
    }
  }
  __syncthreads();
  int t = threadIdx.x;
  if (t < 64){
    float v = (t<32)? lg[t] : -INFINITY;
    float m = wmax(v);
    float e = (t<32)? expf(lg[t]-m) : 0.f;
    float s = wred(e);
    if (t==0){
      ws[PARTM_ + blockIdx.x] = m;
      ws[PARTS_ + blockIdx.x] = s;
    }
  }
}

// Reduce 1000 partials (L2-hot) + write normalized y.
__global__ __launch_bounds__(256) void k_y(const float* __restrict__ ws, float* __restrict__ y){
  __shared__ float rm[4], rs[4];
  int t = threadIdx.x, lane = t&63, wv = t>>6;
  float m = -INFINITY;
  for (int k=t;k<1000;k+=256) m = fmaxf(m, ws[PARTM_+k]);
  m = wmax(m);
  if (lane==0) rm[wv]=m;
  __syncthreads();
  float M = fmaxf(fmaxf(rm[0],rm[1]), fmaxf(rm[2],rm[3]));
  float s = 0.f;
  for (int k=t;k<1000;k+=256) s += ws[PARTS_+k]*expf(ws[PARTM_+k]-M);
  s = wred(s);
  if (lane==0) rs[wv]=s;
  __syncthreads();
  float S = rs[0]+rs[1]+rs[2]+rs[3];
  float off = M + logf(S);
  int i = blockIdx.x*256 + t;   // float4 index, need 8000
  if (i < 8000){
    float4 v = ld4(ws + LOG_ + i*4);
    v.x-=off; v.y-=off; v.z-=off; v.w-=off;
    *(float4*)(y + i*4) = v;
  }
}

extern "C" void kernel_launch(void* const* d_in, const int* in_sizes, int n_in,
                              void* d_out, int out_size, void* d_ws, size_t ws_size,
                              hipStream_t stream) {
  const int*   slen = (const int*)d_in[0];
  const float* enc  = (const float*)d_in[1];
  const int*   word = (const int*)d_in[2];
  const float* h0   = (const float*)d_in[3];
  const float* c0   = (const float*)d_in[4];
  const float* emb  = (const float*)d_in[5];
  const float* wih  = (const float*)d_in[6];
  const float* whh  = (const float*)d_in[7];
  const float* bih  = (const float*)d_in[8];
  const float* bhh  = (const float*)d_in[9];
  const float* a1w  = (const float*)d_in[10];
  const float* a1b  = (const float*)d_in[11];
  const float* a2w  = (const float*)d_in[12];
  const float* a2b  = (const float*)d_in[13];
  const float* f1w  = (const float*)d_in[14];
  const float* f1b  = (const float*)d_in[15];
  const float* f2w  = (const float*)d_in[16];
  const float* f2b  = (const float*)d_in[17];
  float* ws  = (float*)d_ws;
  float* out = (float*)d_out;

  k_lstm0<<<1024,256,0,stream>>>(wih, whh, bih, bhh, word, emb, h0, c0,
                                 ws, out + O_HN, out + O_CN);
  k_lstm1<<<1024,256,0,stream>>>(wih + (size_t)4096*1024, c0 + HDIM,
                                 ws, out + O_HN + HDIM, out + O_CN + HDIM);
  k_att1<<<128,256,0,stream>>>(a1w, a1b, ws);
  k_scores<<<33,256,0,stream>>>(enc, slen, a2w, a2b, ws);
  k_smctx<<<8,128,0,stream>>>(enc, slen, ws, out + O_A);
  k_fc1<<<256,256,0,stream>>>(f1w, f1b, ws, out + O_OUT);
  k_fc2<<<1000,512,0,stream>>>(f2w, f2b, ws);
  k_y<<<32,256,0,stream>>>(ws, out + O_Y);
}